// Round 11
// baseline (129.379 us; speedup 1.0000x reference)
//
#include <hip/hip_runtime.h>
#include <hip/hip_bf16.h>

#define BATCH   32
#define TLEN    128000
#define FGAIN   1000
#define ORDER   26
#define WLEN    512
#define WLEN4   (WLEN/4)            // 128
#define HOP     128
#define PAD     192                 // (512-128)/2
#define TPAD    (TLEN + 2*PAD)      // 128384 padded length
#define NFRAME  1000
#define NTOT    (BATCH*NFRAME)      // 32000 frames total

#define CHUNK   64                  // frames per k_lpc block (= 1 wave)
#define NCHUNK  ((NFRAME + CHUNK - 1) / CHUNK)   // 16 (15 full + tail of 40)
#define XS_SPAN (CHUNK*HOP + WLEN - HOP)         // 8576 floats staged per block
#define XS_LDS  8656                // 8576 + 67 pad + slack
#define GS_LDS  80                  // 72 gain taps needed, padded

// fw_t layout: [BATCH][NCHUNK][WLEN4][CHUNK] float4 = 69.2 MB.
// Lane l stores its frame's samples [t..t+3] at [t/4][l]: a wave64 float4
// store is 64 consecutive float4s = 1024B contiguous = 16 lines (minimum).
// R10 post-mortem: the LDS ys-transpose (512 ds_write + 640 ds_read + 20
// fences/wave, unhidden at 1 wave/SIMD) cost MORE than the 64-line store
// scatter it removed (R5 direct-scatter <=42us vs R6/R10 transpose 52-56us).
// This layout gets coalescing for free; tail-chunk dummy lanes write into
// padding slots (frames 1000..1023) that k_ola never reads.

// ---------------------------------------------------------------------------
// Kernel A: fused (gain-upsample x ex) staging + per-frame order-26 IIR.
// One frame per lane, one wave per block, 64 consecutive frames per block.
// Staging: 8-deep pipelined float4 loads; coefs staged coalesced via LDS;
// ONE __syncthreads total; main loop is pure registers + ds_read + stores.
// ---------------------------------------------------------------------------
__global__ __launch_bounds__(64) void k_lpc(const float* __restrict__ ex,
                                            const float* __restrict__ gain,
                                            const float* __restrict__ acoef,
                                            float4* __restrict__ fwt) {
  __shared__ float xs[XS_LDS];
  __shared__ float gs[GS_LDS];
  __shared__ float as_lin[CHUNK * ORDER];     // 1664 floats, coalesced-staged

  const int lane = threadIdx.x;               // 0..63
  const int cidx = blockIdx.x;                // chunk index 0..15
  const int n0   = cidx * CHUNK;              // first frame of this chunk
  const int b    = blockIdx.y;                // batch row
  const float* __restrict__ exr = ex + (size_t)b * TLEN;
  const float* __restrict__ gr  = gain + b * FGAIN;

  // ---- stage gain taps: i0 range for this chunk is [n0-2, n0+66] ----
  const int GBASE = n0 - 2;
  for (int i = lane; i < 72; i += 64) {
    int gidx = GBASE + i;
    gidx = gidx < 0 ? 0 : (gidx > FGAIN - 1 ? FGAIN - 1 : gidx);
    gs[i] = gr[gidx];
  }
  __syncthreads();                            // gs visible (cheap: nothing inflight)

  // ---- stage coefs coalesced: 416 float4 = frames [n0, n0+64) ----
  {
    const int e0_4 = (b * NFRAME + n0) * ORDER / 4;    // divisible: n0%64==0
    const int lim4 = NTOT * ORDER / 4;                 // 208000
#pragma unroll
    for (int it = 0; it < 7; ++it) {          // 6.5 iterations, unrolled
      int v = lane + 64 * it;
      if (v < CHUNK * ORDER / 4) {
        float4 c = make_float4(0.f, 0.f, 0.f, 0.f);
        if (e0_4 + v < lim4)
          c = *reinterpret_cast<const float4*>(acoef + 4 * (size_t)(e0_4 + v));
        *reinterpret_cast<float4*>(as_lin + 4 * v) = c;
      }
    }
  }

  // ---- stage x = ex * upsample(gain), 8-deep pipelined loads ----
  // All macro locals sc_-prefixed (R9 lesson: caller names must not collide).
  const int sbase = n0 * HOP;
#define STAGE_COMPUTE(IDX4, EVAL) {                                        \
    int sc_s = 4 * (IDX4);                                                 \
    int sc_j = sbase + sc_s - PAD;                                         \
    float sc_v[4] = {0.f, 0.f, 0.f, 0.f};                                  \
    if (sc_j >= 0 && sc_j <= TLEN - 4) {                                   \
      float sc_e[4] = {(EVAL).x, (EVAL).y, (EVAL).z, (EVAL).w};            \
      _Pragma("unroll")                                                    \
      for (int sc_c = 0; sc_c < 4; ++sc_c) {                               \
        float sc_src = ((float)(sc_j + sc_c) + 0.5f) * (1.0f / (float)HOP) \
                       - 0.5f;                                             \
        sc_src = fminf(fmaxf(sc_src, 0.0f), (float)(FGAIN - 1));           \
        int   sc_i0 = (int)sc_src;                                         \
        float sc_w  = sc_src - (float)sc_i0;                               \
        int   sc_i1 = sc_i0 + 1; if (sc_i1 > FGAIN - 1) sc_i1 = FGAIN - 1; \
        float sc_g  = gs[sc_i0 - GBASE] * (1.0f - sc_w)                    \
                    + gs[sc_i1 - GBASE] * sc_w;                            \
        sc_v[sc_c] = sc_e[sc_c] * sc_g;                                    \
      }                                                                    \
    }                                                                      \
    int sc_b = sc_s + (sc_s >> 7);            /* +1 pad per 128 floats */  \
    xs[sc_b + 0] = sc_v[0];  xs[sc_b + 1] = sc_v[1];                       \
    xs[sc_b + 2] = sc_v[2];  xs[sc_b + 3] = sc_v[3];                       \
  }
  for (int g8 = 0; g8 < 4; ++g8) {            // 32 full iterations, 8-deep
    float4 ev[8];
#pragma unroll
    for (int u = 0; u < 8; ++u) {             // issue 8 independent loads
      int gi = lane + 64 * (8 * g8 + u);
      int gj = sbase + 4 * gi - PAD;
      ev[u] = make_float4(0.f, 0.f, 0.f, 0.f);
      if (gj >= 0 && gj <= TLEN - 4)
        ev[u] = *reinterpret_cast<const float4*>(exr + gj);
    }
#pragma unroll
    for (int u = 0; u < 8; ++u) {             // then consume
      STAGE_COMPUTE(lane + 64 * (8 * g8 + u), ev[u])
    }
  }
  {                                           // it = 32 (full)
    int ti = lane + 2048;
    int tj = sbase + 4 * ti - PAD;
    float4 te = make_float4(0.f, 0.f, 0.f, 0.f);
    if (tj >= 0 && tj <= TLEN - 4)
      te = *reinterpret_cast<const float4*>(exr + tj);
    STAGE_COMPUTE(ti, te)
  }
  if (lane < XS_SPAN / 4 - 2112) {            // it = 33 (partial: lane < 32)
    int ti = lane + 2112;
    int tj = sbase + 4 * ti - PAD;
    float4 te = make_float4(0.f, 0.f, 0.f, 0.f);
    if (tj >= 0 && tj <= TLEN - 4)
      te = *reinterpret_cast<const float4*>(exr + tj);
    STAGE_COMPUTE(ti, te)
  }
#undef STAGE_COMPUTE
  __syncthreads();                            // xs + as_lin visible (only sync)

  // ---- per-lane frame setup (coefs from LDS, ds_read_b64) ----
  float a[ORDER], h[ORDER];
  {
    const float* __restrict__ al = as_lin + lane * ORDER;  // 8B-aligned
#pragma unroll
    for (int q = 0; q < 13; ++q) {
      float2 v = *reinterpret_cast<const float2*>(al + 2 * q);
      a[2 * q] = v.x;  a[2 * q + 1] = v.y;
    }
  }
#pragma unroll
  for (int k = 0; k < ORDER; ++k) h[k] = 0.0f;

  // per-block store base: fw_t[b][cidx][.][.]
  float4* __restrict__ fwt_blk = fwt + (size_t)(b * NCHUNK + cidx) * WLEN4 * CHUNK;
  float buf[52];

  // Invariant at step s (t % 26 == 0): h[m] holds the newest y at time
  // congruent to m (mod 26). Need y[t+s-1-k] -> slot ((s-1-k) mod 26).
  // Tap 0 applied LAST: cross-step critical path is a single FMA.
#define LPC_STEP(s) {                                                      \
    float xv = buf[(s)];                                                   \
    float p0 = xv, p1 = 0.f, p2 = 0.f, p3 = 0.f;                           \
    _Pragma("unroll")                                                      \
    for (int k = 1; k < ORDER; ++k) {                                      \
      float hv = h[((s) - 1 - k + 2 * ORDER) % ORDER];                     \
      int sel = k & 3;                                                     \
      if      (sel == 0) p0 -= a[k] * hv;                                  \
      else if (sel == 1) p1 -= a[k] * hv;                                  \
      else if (sel == 2) p2 -= a[k] * hv;                                  \
      else               p3 -= a[k] * hv;                                  \
    }                                                                      \
    float rest = (p0 + p1) + (p2 + p3);                                    \
    float y = rest - a[0] * h[((s) + ORDER - 1) % ORDER];                  \
    h[(s) % ORDER] = y;                                                    \
    buf[(s)] = y;                                                          \
  }

#define LOAD_BUF(nq) {                                                     \
    _Pragma("unroll")                                                      \
    for (int q = 0; q < (nq); ++q) {                                       \
      int u = t + 4 * q;                                                   \
      int base = lane * 129 + u + (u >> 7);                                \
      buf[4 * q + 0] = xs[base + 0];                                       \
      buf[4 * q + 1] = xs[base + 1];                                       \
      buf[4 * q + 2] = xs[base + 2];                                       \
      buf[4 * q + 3] = xs[base + 3];                                       \
    }                                                                      \
  }

  // Coalesced store into fw_t: lane-contiguous 1024B per instruction.
#define STORE_BUF(nq) {                                                    \
    _Pragma("unroll")                                                      \
    for (int q = 0; q < (nq); ++q) {                                       \
      fwt_blk[(size_t)((t >> 2) + q) * CHUNK + lane] =                     \
          make_float4(buf[4 * q + 0], buf[4 * q + 1],                      \
                      buf[4 * q + 2], buf[4 * q + 3]);                     \
    }                                                                      \
  }

  int t = 0;
  for (int sb = 0; sb < 9; ++sb) {            // 9 * 52 = 468
    LOAD_BUF(13)
#pragma unroll
    for (int s = 0; s < 52; ++s) {
      LPC_STEP(s)
    }
    STORE_BUF(13)
    t += 52;
  }
  // epilogue: t = 468 (468 % 26 == 0), 44 remaining steps = 11 x float4
  LOAD_BUF(11)
#pragma unroll
  for (int s = 0; s < 44; ++s) {
    LPC_STEP(s)
  }
  STORE_BUF(11)
#undef LPC_STEP
#undef LOAD_BUF
#undef STORE_BUF
}

// ---------------------------------------------------------------------------
// Kernel B: windowed overlap-add + normalization, reading the fw_t layout.
// out[b][j] = ( sum_n fw[b][n][w0] * win[w0] ) / ( sum_n win[w0] ),
// w0 = j + PAD - 128n. 4 outputs per thread; w0 is a multiple of 4, so each
// read is one aligned float4 at fw_t[b][n>>6][w0>>2][n&63]. Per-lane stride
// is 1024B (scattered), but all fetched bytes are used (4x L1 reuse within
// the block) and 8000 blocks of TLP hide the latency.
// ---------------------------------------------------------------------------
__global__ __launch_bounds__(256) void k_ola(const float4* __restrict__ fwt,
                                             const float* __restrict__ win,
                                             float* __restrict__ out) {
  int gid = blockIdx.x * 256 + threadIdx.x;   // one thread per 4 outputs
  const int total4 = BATCH * TLEN / 4;
  if (gid >= total4) return;
  int idx = gid * 4;
  int b  = idx / TLEN;
  int j0 = idx - b * TLEN;
  int p0 = j0 + PAD;

  // frames n with 0 <= p0-128n <= 508:  ceil((p0-508)/128) == (p0-381)/128
  int lo = (p0 - 381) / HOP;
  if (lo < 0) lo = 0;
  int hi = p0 / HOP;
  if (hi > NFRAME - 1) hi = NFRAME - 1;

  const size_t brow = (size_t)b * NCHUNK * WLEN4 * CHUNK;
  float ax = 0.f, ay = 0.f, az = 0.f, aw = 0.f;
  float nx = 0.f, ny = 0.f, nz = 0.f, nw = 0.f;
  for (int n = lo; n <= hi; ++n) {
    int w0 = p0 - n * HOP;       // 0..508, multiple of 4
    float4 fv = fwt[brow + ((size_t)(n >> 6) * WLEN4 + (w0 >> 2)) * CHUNK + (n & 63)];
    const float4 wv = *reinterpret_cast<const float4*>(win + w0);
    ax += fv.x * wv.x;  ay += fv.y * wv.y;  az += fv.z * wv.z;  aw += fv.w * wv.w;
    nx += wv.x;         ny += wv.y;         nz += wv.z;         nw += wv.w;
  }
  float4 o = make_float4(ax / nx, ay / ny, az / nz, aw / nw);
  *reinterpret_cast<float4*>(out + idx) = o;
}

// ---------------------------------------------------------------------------
extern "C" void kernel_launch(void* const* d_in, const int* in_sizes, int n_in,
                              void* d_out, int out_size, void* d_ws, size_t ws_size,
                              hipStream_t stream) {
  const float* ex   = (const float*)d_in[0];   // [32][128000]
  const float* gain = (const float*)d_in[1];   // [32][1000]
  const float* a    = (const float*)d_in[2];   // [32][1000][26]
  const float* win  = (const float*)d_in[3];   // [512]
  // d_in[4] = hop_length (=128, compile-time constant here)
  float* outp = (float*)d_out;                 // [32][128000]

  // workspace: fw_t [32][16][128][64] float4 = 69.2 MB
  float4* fwt = (float4*)d_ws;

  {
    hipLaunchKernelGGL(k_lpc, dim3(NCHUNK, BATCH), dim3(64), 0, stream,
                       ex, gain, a, fwt);
  }
  {
    int total4 = BATCH * TLEN / 4;
    int blocks = (total4 + 255) / 256;
    hipLaunchKernelGGL(k_ola, dim3(blocks), dim3(256), 0, stream, fwt, win, outp);
  }
}